// Round 12
// baseline (195.114 us; speedup 1.0000x reference)
//
#include <hip/hip_runtime.h>
#include <hip/hip_fp16.h>

// MinGRU stack: 3x (APL z/h + linear recurrence + maxabs-normalize) + APL out.
// B=8, T=2048, Din=D=Dout=64, P=16 knots on [-1,1].
// Structure = round 11 (best passing, 186 us) with one change:
//   Layer 3's z-table packed f16x2 (rel 5e-4; error amplified only ~21x by
//   the out layer -> ~0.01 added absmax). Layers 1-2 stay full f32 float4
//   (bf16/f16 there is amplified ~600x -> fails; round-10 evidence).
//   Output table f16x2 (was bf16x2; same bytes, 8x tighter).
// APL: direct L2 gather, one wave/sample, per-lane (offset,frac) shuffled,
// 4-deep batched. Scan: separate pass1 / fixup / pass2.
// Prep kernels kept separate (round-6 post-timing note).

#define WPB 8   // waves (samples) per block in APL kernels (512 threads)
#define NC 64   // chunks per sequence
#define CL 32   // timesteps per chunk (NC*CL == T == 2048)

__device__ __forceinline__ unsigned int pack_f16(float lo, float hi) {
    return (unsigned int)__half_as_ushort(__float2half(lo))
         | ((unsigned int)__half_as_ushort(__float2half(hi)) << 16);
}
__device__ __forceinline__ float unpack_f16_lo(unsigned int u) {
    return __half2float(__ushort_as_half((unsigned short)(u & 0xffffu)));
}
__device__ __forceinline__ float unpack_f16_hi(unsigned int u) {
    return __half2float(__ushort_as_half((unsigned short)(u >> 16)));
}

// ---- table prep (layers 1-2): float4(z0, dz, h0, dh), all f32 ----
__global__ __launch_bounds__(256) void prep_dual_kernel(
    const float* __restrict__ vz, const float* __restrict__ vh,
    float4* __restrict__ tab)
{
    int idx = blockIdx.x * blockDim.x + threadIdx.x;   // over 64*15*64
    if (idx >= 64 * 15 * 64) return;
    int o = idx & 63;
    int p = (idx >> 6) % 15;
    int i = idx / (15 * 64);
    int base = (i * 16 + p) * 64 + o;
    float z0 = vz[base], z1 = vz[base + 64];
    float h0 = vh[base], h1 = vh[base + 64];
    tab[idx] = make_float4(z0, z1 - z0, h0, h1 - h0);
}

// ---- table prep (layer 3): h f32 float2 + z packed f16x2 ----
__global__ __launch_bounds__(256) void prep_dual_l3_kernel(
    const float* __restrict__ vz, const float* __restrict__ vh,
    float2* __restrict__ htab, unsigned int* __restrict__ ztab)
{
    int idx = blockIdx.x * blockDim.x + threadIdx.x;
    if (idx >= 64 * 15 * 64) return;
    int o = idx & 63;
    int p = (idx >> 6) % 15;
    int i = idx / (15 * 64);
    int base = (i * 16 + p) * 64 + o;
    float z0 = vz[base], z1 = vz[base + 64];
    float h0 = vh[base], h1 = vh[base + 64];
    htab[idx] = make_float2(h0, h1 - h0);
    ztab[idx] = pack_f16(z0, z1 - z0);
}

// output table: packed f16x2 (v0 low, dv high)
__global__ __launch_bounds__(256) void prep_out_kernel(
    const float* __restrict__ v, unsigned int* __restrict__ tab)
{
    int idx = blockIdx.x * blockDim.x + threadIdx.x;
    if (idx >= 64 * 15 * 64) return;
    int o = idx & 63;
    int p = (idx >> 6) % 15;
    int i = idx / (15 * 64);
    int base = (i * 16 + p) * 64 + o;
    float v0 = v[base], v1 = v[base + 64];
    tab[idx] = pack_f16(v0, v1 - v0);
}

// ---- APL (dual, f32 table; layers 1-2) ----
__global__ __launch_bounds__(512) void apl_dual_kernel(
    const float* __restrict__ in, const float4* __restrict__ tab,
    float2* __restrict__ zh, int N)
{
    const int lane = threadIdx.x & 63;
    const int n = blockIdx.x * WPB + (threadIdx.x >> 6);
    if (n >= N) return;

    float xv = in[(size_t)n * 64 + lane];
    float tv = fminf(fmaxf(xv, -1.f), 1.f) * 7.5f + 7.5f;   // [0,15]
    int iv = (int)tv; iv = iv > 14 ? 14 : iv;
    float frv = tv - (float)iv;
    int offv = lane * 15360 + (iv << 10);   // dim-l row byte offset

    const char* tb = (const char*)tab + lane * 16;
    float accz0 = 0.f, acch0 = 0.f, accz1 = 0.f, acch1 = 0.f;
#pragma unroll
    for (int i0 = 0; i0 < 64; i0 += 4) {
        int of0 = __shfl(offv, i0 + 0, 64);
        int of1 = __shfl(offv, i0 + 1, 64);
        int of2 = __shfl(offv, i0 + 2, 64);
        int of3 = __shfl(offv, i0 + 3, 64);
        float fr0 = __shfl(frv, i0 + 0, 64);
        float fr1 = __shfl(frv, i0 + 1, 64);
        float fr2 = __shfl(frv, i0 + 2, 64);
        float fr3 = __shfl(frv, i0 + 3, 64);
        float4 e0 = *(const float4*)(tb + of0);
        float4 e1 = *(const float4*)(tb + of1);
        float4 e2 = *(const float4*)(tb + of2);
        float4 e3 = *(const float4*)(tb + of3);
        accz0 += fmaf(fr0, e0.y, e0.x);
        acch0 += fmaf(fr0, e0.w, e0.z);
        accz1 += fmaf(fr1, e1.y, e1.x);
        acch1 += fmaf(fr1, e1.w, e1.z);
        accz0 += fmaf(fr2, e2.y, e2.x);
        acch0 += fmaf(fr2, e2.w, e2.z);
        accz1 += fmaf(fr3, e3.y, e3.x);
        acch1 += fmaf(fr3, e3.w, e3.z);
    }
    float accz = accz0 + accz1, acch = acch0 + acch1;
    float z = 1.f / (1.f + expf(-accz));
    zh[(size_t)n * 64 + lane] = make_float2(z, acch);
}

// ---- APL (dual, layer 3): h f32 float2 + z f16x2 -> 12 B/lane/iter ----
__global__ __launch_bounds__(512) void apl_dual_l3_kernel(
    const float* __restrict__ in, const float2* __restrict__ htab,
    const unsigned int* __restrict__ ztab,
    float2* __restrict__ zh, int N)
{
    const int lane = threadIdx.x & 63;
    const int n = blockIdx.x * WPB + (threadIdx.x >> 6);
    if (n >= N) return;

    float xv = in[(size_t)n * 64 + lane];
    float tv = fminf(fmaxf(xv, -1.f), 1.f) * 7.5f + 7.5f;
    int iv = (int)tv; iv = iv > 14 ? 14 : iv;
    float frv = tv - (float)iv;
    // h-table byte offset: float2 rows = 512 B, 15*512 = 7680 per dim
    int offv = lane * 7680 + (iv << 9);

    const char* hb = (const char*)htab + lane * 8;
    const char* zb = (const char*)ztab + lane * 4;   // uint rows = offv >> 1
    float accz0 = 0.f, acch0 = 0.f, accz1 = 0.f, acch1 = 0.f;
#pragma unroll
    for (int i0 = 0; i0 < 64; i0 += 4) {
        int oh0 = __shfl(offv, i0 + 0, 64);
        int oh1 = __shfl(offv, i0 + 1, 64);
        int oh2 = __shfl(offv, i0 + 2, 64);
        int oh3 = __shfl(offv, i0 + 3, 64);
        float fr0 = __shfl(frv, i0 + 0, 64);
        float fr1 = __shfl(frv, i0 + 1, 64);
        float fr2 = __shfl(frv, i0 + 2, 64);
        float fr3 = __shfl(frv, i0 + 3, 64);
        float2 h0 = *(const float2*)(hb + oh0);
        float2 h1 = *(const float2*)(hb + oh1);
        float2 h2 = *(const float2*)(hb + oh2);
        float2 h3 = *(const float2*)(hb + oh3);
        unsigned int z0 = *(const unsigned int*)(zb + (oh0 >> 1));
        unsigned int z1 = *(const unsigned int*)(zb + (oh1 >> 1));
        unsigned int z2 = *(const unsigned int*)(zb + (oh2 >> 1));
        unsigned int z3 = *(const unsigned int*)(zb + (oh3 >> 1));
        acch0 += fmaf(fr0, h0.y, h0.x);
        acch1 += fmaf(fr1, h1.y, h1.x);
        acch0 += fmaf(fr2, h2.y, h2.x);
        acch1 += fmaf(fr3, h3.y, h3.x);
        accz0 += fmaf(fr0, unpack_f16_hi(z0), unpack_f16_lo(z0));
        accz1 += fmaf(fr1, unpack_f16_hi(z1), unpack_f16_lo(z1));
        accz0 += fmaf(fr2, unpack_f16_hi(z2), unpack_f16_lo(z2));
        accz1 += fmaf(fr3, unpack_f16_hi(z3), unpack_f16_lo(z3));
    }
    float accz = accz0 + accz1, acch = acch0 + acch1;
    float z = 1.f / (1.f + expf(-accz));
    zh[(size_t)n * 64 + lane] = make_float2(z, acch);
}

// ---- APL (f16x2 table, output layer), 8-deep load batching ----
__global__ __launch_bounds__(512) void apl_out_kernel(
    const float* __restrict__ in, const unsigned int* __restrict__ tab,
    float* __restrict__ out, int N)
{
    const int lane = threadIdx.x & 63;
    const int n = blockIdx.x * WPB + (threadIdx.x >> 6);
    if (n >= N) return;

    float xv = in[(size_t)n * 64 + lane];
    float tv = fminf(fmaxf(xv, -1.f), 1.f) * 7.5f + 7.5f;
    int iv = (int)tv; iv = iv > 14 ? 14 : iv;
    float frv = tv - (float)iv;
    int offv = lane * 3840 + (iv << 8);   // uint rows: 256B; 15*256 per dim

    const char* tb = (const char*)tab + lane * 4;
    float acc0 = 0.f, acc1 = 0.f;
#pragma unroll
    for (int i0 = 0; i0 < 64; i0 += 8) {
        int of[8]; float fr[8]; unsigned int e[8];
#pragma unroll
        for (int j = 0; j < 8; ++j) of[j] = __shfl(offv, i0 + j, 64);
#pragma unroll
        for (int j = 0; j < 8; ++j) fr[j] = __shfl(frv, i0 + j, 64);
#pragma unroll
        for (int j = 0; j < 8; ++j) e[j] = *(const unsigned int*)(tb + of[j]);
#pragma unroll
        for (int j = 0; j < 8; j += 2) {
            acc0 += fmaf(fr[j], unpack_f16_hi(e[j]), unpack_f16_lo(e[j]));
            acc1 += fmaf(fr[j + 1], unpack_f16_hi(e[j + 1]), unpack_f16_lo(e[j + 1]));
        }
    }
    out[(size_t)n * 64 + lane] = acc0 + acc1;
}

// ---- scan pass 1: per-chunk affine summary (A, B): h_out = A*h_in + B ----
__global__ __launch_bounds__(256) void scan_pass1_kernel(
    const float2* __restrict__ zh, float2* __restrict__ chunkAB, int T)
{
    int lane = threadIdx.x & 63;
    int wid = blockIdx.x * (blockDim.x >> 6) + (threadIdx.x >> 6);  // b*NC + c
    int b = wid / NC, c = wid % NC;
    const float2* p = zh + ((size_t)b * T + (size_t)c * CL) * 64 + lane;

    float A = 1.f, Bc = 0.f;
    for (int k0 = 0; k0 < CL; k0 += 8) {
        float2 v[8];
#pragma unroll
        for (int k = 0; k < 8; ++k) v[k] = p[(size_t)(k0 + k) * 64];
#pragma unroll
        for (int k = 0; k < 8; ++k) {
            float a = 1.f - v[k].x;
            float bb = v[k].x * v[k].y;
            A *= a;
            Bc = fmaf(a, Bc, bb);
        }
    }
    chunkAB[(size_t)wid * 64 + lane] = make_float2(A, Bc);
}

// ---- scan fixup: sequential combine of NC chunk summaries per (b, d) ----
__global__ __launch_bounds__(64) void scan_fixup_kernel(
    const float2* __restrict__ chunkAB, float* __restrict__ hinit)
{
    int b = blockIdx.x;
    int d = threadIdx.x;
    const float2* p = chunkAB + (size_t)b * NC * 64 + d;
    float* o = hinit + (size_t)b * NC * 64 + d;

    float h = 0.f;  // h0 = 0
    for (int c0 = 0; c0 < NC; c0 += 8) {
        float2 ab[8];
#pragma unroll
        for (int k = 0; k < 8; ++k) ab[k] = p[(size_t)(c0 + k) * 64];
#pragma unroll
        for (int k = 0; k < 8; ++k) {
            o[(size_t)(c0 + k) * 64] = h;
            h = fmaf(ab[k].x, h, ab[k].y);
        }
    }
}

// ---- scan pass 2: replay chunk from hinit, fused maxabs-normalize ----
__global__ __launch_bounds__(256) void scan_pass2_kernel(
    const float2* __restrict__ zh, const float* __restrict__ hinit,
    float* __restrict__ out, int T)
{
    int lane = threadIdx.x & 63;
    int wid = blockIdx.x * (blockDim.x >> 6) + (threadIdx.x >> 6);  // b*NC + c
    int b = wid / NC, c = wid % NC;
    const float2* p = zh + ((size_t)b * T + (size_t)c * CL) * 64 + lane;
    float* o = out + ((size_t)b * T + (size_t)c * CL) * 64 + lane;

    float h = hinit[(size_t)wid * 64 + lane];
    for (int k0 = 0; k0 < CL; k0 += 8) {
        float2 v[8];
        float hs[8];
#pragma unroll
        for (int k = 0; k < 8; ++k) v[k] = p[(size_t)(k0 + k) * 64];
#pragma unroll
        for (int k = 0; k < 8; ++k) {
            h = fmaf(v[k].x, v[k].y - h, h);   // h += z*(hbar - h)
            hs[k] = h;
        }
#pragma unroll
        for (int k = 0; k < 8; ++k) {
            float m = fabsf(hs[k]);
            m = fmaxf(m, __shfl_xor(m, 32, 64));
            m = fmaxf(m, __shfl_xor(m, 16, 64));
            m = fmaxf(m, __shfl_xor(m, 8, 64));
            m = fmaxf(m, __shfl_xor(m, 4, 64));
            m = fmaxf(m, __shfl_xor(m, 2, 64));
            m = fmaxf(m, __shfl_xor(m, 1, 64));
            o[(size_t)(k0 + k) * 64] = hs[k] / (m + 1e-6f);
        }
    }
}

extern "C" void kernel_launch(void* const* d_in, const int* in_sizes, int n_in,
                              void* d_out, int out_size, void* d_ws, size_t ws_size,
                              hipStream_t stream) {
    const float* x    = (const float*)d_in[0];
    const float* vz0  = (const float*)d_in[1];
    const float* vh0  = (const float*)d_in[2];
    const float* vz1  = (const float*)d_in[3];
    const float* vh1  = (const float*)d_in[4];
    const float* vz2  = (const float*)d_in[5];
    const float* vh2  = (const float*)d_in[6];
    const float* vout = (const float*)d_in[7];

    const int N = in_sizes[0] / 64;   // B*T = 16384
    const int T = NC * CL;            // 2048
    const int B = N / T;              // 8

    char* ws = (char*)d_ws;
    const size_t TAB_ELEMS = (size_t)64 * 15 * 64;   // 61440
    float2* zh      = (float2*)ws;                                  // 8 MB
    float*  cur     = (float*)(ws + 8388608);                       // 4 MB
    float4* tab0    = (float4*)(ws + 12582912);                     // 960 KB
    float4* tab1    = (float4*)(ws + 13565952);                     // 960 KB
    float2* htab2   = (float2*)(ws + 14548992);                     // 480 KB
    unsigned int* ztab2 = (unsigned int*)(ws + 15040512);           // 240 KB
    unsigned int* tab_out = (unsigned int*)(ws + 15286272);         // 240 KB
    float2* chunkAB = (float2*)(ws + 15532032);                     // 256 KB
    float*  hinit   = (float*)(ws + 15794176);                      // 128 KB

    dim3 pblk(256), pgrd((TAB_ELEMS + 255) / 256);
    prep_dual_kernel<<<pgrd, pblk, 0, stream>>>(vz0, vh0, tab0);
    prep_dual_kernel<<<pgrd, pblk, 0, stream>>>(vz1, vh1, tab1);
    prep_dual_l3_kernel<<<pgrd, pblk, 0, stream>>>(vz2, vh2, htab2, ztab2);
    prep_out_kernel<<<pgrd, pblk, 0, stream>>>(vout, tab_out);

    dim3 ablk(64 * WPB), agrd((N + WPB - 1) / WPB);
    dim3 sblk(256), sgrd(B * NC / 4);   // 4 waves (chunks) per block

    const float* layer_in = x;
    for (int l = 0; l < 3; ++l) {
        if (l < 2) {
            const float4* tab = (l == 0) ? tab0 : tab1;
            apl_dual_kernel<<<agrd, ablk, 0, stream>>>(layer_in, tab, zh, N);
        } else {
            apl_dual_l3_kernel<<<agrd, ablk, 0, stream>>>(layer_in, htab2, ztab2, zh, N);
        }
        scan_pass1_kernel<<<sgrd, sblk, 0, stream>>>(zh, chunkAB, T);
        scan_fixup_kernel<<<B, 64, 0, stream>>>(chunkAB, hinit);
        scan_pass2_kernel<<<sgrd, sblk, 0, stream>>>(zh, hinit, cur, T);
        layer_in = cur;
    }
    apl_out_kernel<<<agrd, ablk, 0, stream>>>(cur, tab_out, (float*)d_out, N);
}

// Round 14
// 184.600 us; speedup vs baseline: 1.0570x; 1.0570x over previous
//
#include <hip/hip_runtime.h>
#include <hip/hip_fp16.h>

// MinGRU stack: 3x (APL z/h + linear recurrence + maxabs-normalize) + APL out.
// B=8, T=2048, Din=D=Dout=64, P=16 knots on [-1,1].
// Structure = round 11 (best passing, 186 us) with one change:
//   Layer 3's table is FULL f16 packed into ONE uint2 (8 B/lane/iter, single
//   load). Round-12 lesson: splitting into 2 loads (12B) was SLOWER than one
//   16B load -- gather cost is dominated by load-instruction count, then
//   bytes. f16 h at layer 3: ~2e-3 error x ~21 (out layer only) ~= +0.04.
//   Layers 1-2 stay f32 float4 (round-10: bf16 z there -> 2.37 absmax fail).
//   Output table f16x2 (proven).
// APL: direct L2 gather, one wave/sample, per-lane (offset,frac) shuffled,
// 4-deep batched. Scan: separate pass1 / fixup / pass2.
// Prep kernels kept separate (round-6 post-timing note).

#define WPB 8   // waves (samples) per block in APL kernels (512 threads)
#define NC 64   // chunks per sequence
#define CL 32   // timesteps per chunk (NC*CL == T == 2048)

__device__ __forceinline__ unsigned int pack_f16(float lo, float hi) {
    return (unsigned int)__half_as_ushort(__float2half(lo))
         | ((unsigned int)__half_as_ushort(__float2half(hi)) << 16);
}
__device__ __forceinline__ float unpack_f16_lo(unsigned int u) {
    return __half2float(__ushort_as_half((unsigned short)(u & 0xffffu)));
}
__device__ __forceinline__ float unpack_f16_hi(unsigned int u) {
    return __half2float(__ushort_as_half((unsigned short)(u >> 16)));
}

// ---- table prep (layers 1-2): float4(z0, dz, h0, dh), all f32 ----
__global__ __launch_bounds__(256) void prep_dual_kernel(
    const float* __restrict__ vz, const float* __restrict__ vh,
    float4* __restrict__ tab)
{
    int idx = blockIdx.x * blockDim.x + threadIdx.x;   // over 64*15*64
    if (idx >= 64 * 15 * 64) return;
    int o = idx & 63;
    int p = (idx >> 6) % 15;
    int i = idx / (15 * 64);
    int base = (i * 16 + p) * 64 + o;
    float z0 = vz[base], z1 = vz[base + 64];
    float h0 = vh[base], h1 = vh[base + 64];
    tab[idx] = make_float4(z0, z1 - z0, h0, h1 - h0);
}

// ---- table prep (layer 3): uint2 = (f16 z0|dz, f16 h0|dh) ----
__global__ __launch_bounds__(256) void prep_dual_l3_kernel(
    const float* __restrict__ vz, const float* __restrict__ vh,
    uint2* __restrict__ tab)
{
    int idx = blockIdx.x * blockDim.x + threadIdx.x;
    if (idx >= 64 * 15 * 64) return;
    int o = idx & 63;
    int p = (idx >> 6) % 15;
    int i = idx / (15 * 64);
    int base = (i * 16 + p) * 64 + o;
    float z0 = vz[base], z1 = vz[base + 64];
    float h0 = vh[base], h1 = vh[base + 64];
    tab[idx] = make_uint2(pack_f16(z0, z1 - z0), pack_f16(h0, h1 - h0));
}

// output table: packed f16x2 (v0 low, dv high)
__global__ __launch_bounds__(256) void prep_out_kernel(
    const float* __restrict__ v, unsigned int* __restrict__ tab)
{
    int idx = blockIdx.x * blockDim.x + threadIdx.x;
    if (idx >= 64 * 15 * 64) return;
    int o = idx & 63;
    int p = (idx >> 6) % 15;
    int i = idx / (15 * 64);
    int base = (i * 16 + p) * 64 + o;
    float v0 = v[base], v1 = v[base + 64];
    tab[idx] = pack_f16(v0, v1 - v0);
}

// ---- APL (dual, f32 table; layers 1-2) ----
__global__ __launch_bounds__(512) void apl_dual_kernel(
    const float* __restrict__ in, const float4* __restrict__ tab,
    float2* __restrict__ zh, int N)
{
    const int lane = threadIdx.x & 63;
    const int n = blockIdx.x * WPB + (threadIdx.x >> 6);
    if (n >= N) return;

    float xv = in[(size_t)n * 64 + lane];
    float tv = fminf(fmaxf(xv, -1.f), 1.f) * 7.5f + 7.5f;   // [0,15]
    int iv = (int)tv; iv = iv > 14 ? 14 : iv;
    float frv = tv - (float)iv;
    int offv = lane * 15360 + (iv << 10);   // dim-l row byte offset

    const char* tb = (const char*)tab + lane * 16;
    float accz0 = 0.f, acch0 = 0.f, accz1 = 0.f, acch1 = 0.f;
#pragma unroll
    for (int i0 = 0; i0 < 64; i0 += 4) {
        int of0 = __shfl(offv, i0 + 0, 64);
        int of1 = __shfl(offv, i0 + 1, 64);
        int of2 = __shfl(offv, i0 + 2, 64);
        int of3 = __shfl(offv, i0 + 3, 64);
        float fr0 = __shfl(frv, i0 + 0, 64);
        float fr1 = __shfl(frv, i0 + 1, 64);
        float fr2 = __shfl(frv, i0 + 2, 64);
        float fr3 = __shfl(frv, i0 + 3, 64);
        float4 e0 = *(const float4*)(tb + of0);
        float4 e1 = *(const float4*)(tb + of1);
        float4 e2 = *(const float4*)(tb + of2);
        float4 e3 = *(const float4*)(tb + of3);
        accz0 += fmaf(fr0, e0.y, e0.x);
        acch0 += fmaf(fr0, e0.w, e0.z);
        accz1 += fmaf(fr1, e1.y, e1.x);
        acch1 += fmaf(fr1, e1.w, e1.z);
        accz0 += fmaf(fr2, e2.y, e2.x);
        acch0 += fmaf(fr2, e2.w, e2.z);
        accz1 += fmaf(fr3, e3.y, e3.x);
        acch1 += fmaf(fr3, e3.w, e3.z);
    }
    float accz = accz0 + accz1, acch = acch0 + acch1;
    float z = 1.f / (1.f + expf(-accz));
    zh[(size_t)n * 64 + lane] = make_float2(z, acch);
}

// ---- APL (dual, layer 3): full f16 uint2 rows -> ONE 8B load per iter ----
__global__ __launch_bounds__(512) void apl_dual_l3_kernel(
    const float* __restrict__ in, const uint2* __restrict__ tab,
    float2* __restrict__ zh, int N)
{
    const int lane = threadIdx.x & 63;
    const int n = blockIdx.x * WPB + (threadIdx.x >> 6);
    if (n >= N) return;

    float xv = in[(size_t)n * 64 + lane];
    float tv = fminf(fmaxf(xv, -1.f), 1.f) * 7.5f + 7.5f;
    int iv = (int)tv; iv = iv > 14 ? 14 : iv;
    float frv = tv - (float)iv;
    // uint2 rows: 64*8 = 512 B per row, 15*512 = 7680 B per dim
    int offv = lane * 7680 + (iv << 9);

    const char* tb = (const char*)tab + lane * 8;
    float accz0 = 0.f, acch0 = 0.f, accz1 = 0.f, acch1 = 0.f;
#pragma unroll
    for (int i0 = 0; i0 < 64; i0 += 4) {
        int of0 = __shfl(offv, i0 + 0, 64);
        int of1 = __shfl(offv, i0 + 1, 64);
        int of2 = __shfl(offv, i0 + 2, 64);
        int of3 = __shfl(offv, i0 + 3, 64);
        float fr0 = __shfl(frv, i0 + 0, 64);
        float fr1 = __shfl(frv, i0 + 1, 64);
        float fr2 = __shfl(frv, i0 + 2, 64);
        float fr3 = __shfl(frv, i0 + 3, 64);
        uint2 e0 = *(const uint2*)(tb + of0);
        uint2 e1 = *(const uint2*)(tb + of1);
        uint2 e2 = *(const uint2*)(tb + of2);
        uint2 e3 = *(const uint2*)(tb + of3);
        accz0 += fmaf(fr0, unpack_f16_hi(e0.x), unpack_f16_lo(e0.x));
        acch0 += fmaf(fr0, unpack_f16_hi(e0.y), unpack_f16_lo(e0.y));
        accz1 += fmaf(fr1, unpack_f16_hi(e1.x), unpack_f16_lo(e1.x));
        acch1 += fmaf(fr1, unpack_f16_hi(e1.y), unpack_f16_lo(e1.y));
        accz0 += fmaf(fr2, unpack_f16_hi(e2.x), unpack_f16_lo(e2.x));
        acch0 += fmaf(fr2, unpack_f16_hi(e2.y), unpack_f16_lo(e2.y));
        accz1 += fmaf(fr3, unpack_f16_hi(e3.x), unpack_f16_lo(e3.x));
        acch1 += fmaf(fr3, unpack_f16_hi(e3.y), unpack_f16_lo(e3.y));
    }
    float accz = accz0 + accz1, acch = acch0 + acch1;
    float z = 1.f / (1.f + expf(-accz));
    zh[(size_t)n * 64 + lane] = make_float2(z, acch);
}

// ---- APL (f16x2 table, output layer), 8-deep load batching ----
__global__ __launch_bounds__(512) void apl_out_kernel(
    const float* __restrict__ in, const unsigned int* __restrict__ tab,
    float* __restrict__ out, int N)
{
    const int lane = threadIdx.x & 63;
    const int n = blockIdx.x * WPB + (threadIdx.x >> 6);
    if (n >= N) return;

    float xv = in[(size_t)n * 64 + lane];
    float tv = fminf(fmaxf(xv, -1.f), 1.f) * 7.5f + 7.5f;
    int iv = (int)tv; iv = iv > 14 ? 14 : iv;
    float frv = tv - (float)iv;
    int offv = lane * 3840 + (iv << 8);   // uint rows: 256B; 15*256 per dim

    const char* tb = (const char*)tab + lane * 4;
    float acc0 = 0.f, acc1 = 0.f;
#pragma unroll
    for (int i0 = 0; i0 < 64; i0 += 8) {
        int of[8]; float fr[8]; unsigned int e[8];
#pragma unroll
        for (int j = 0; j < 8; ++j) of[j] = __shfl(offv, i0 + j, 64);
#pragma unroll
        for (int j = 0; j < 8; ++j) fr[j] = __shfl(frv, i0 + j, 64);
#pragma unroll
        for (int j = 0; j < 8; ++j) e[j] = *(const unsigned int*)(tb + of[j]);
#pragma unroll
        for (int j = 0; j < 8; j += 2) {
            acc0 += fmaf(fr[j], unpack_f16_hi(e[j]), unpack_f16_lo(e[j]));
            acc1 += fmaf(fr[j + 1], unpack_f16_hi(e[j + 1]), unpack_f16_lo(e[j + 1]));
        }
    }
    out[(size_t)n * 64 + lane] = acc0 + acc1;
}

// ---- scan pass 1: per-chunk affine summary (A, B): h_out = A*h_in + B ----
__global__ __launch_bounds__(256) void scan_pass1_kernel(
    const float2* __restrict__ zh, float2* __restrict__ chunkAB, int T)
{
    int lane = threadIdx.x & 63;
    int wid = blockIdx.x * (blockDim.x >> 6) + (threadIdx.x >> 6);  // b*NC + c
    int b = wid / NC, c = wid % NC;
    const float2* p = zh + ((size_t)b * T + (size_t)c * CL) * 64 + lane;

    float A = 1.f, Bc = 0.f;
    for (int k0 = 0; k0 < CL; k0 += 8) {
        float2 v[8];
#pragma unroll
        for (int k = 0; k < 8; ++k) v[k] = p[(size_t)(k0 + k) * 64];
#pragma unroll
        for (int k = 0; k < 8; ++k) {
            float a = 1.f - v[k].x;
            float bb = v[k].x * v[k].y;
            A *= a;
            Bc = fmaf(a, Bc, bb);
        }
    }
    chunkAB[(size_t)wid * 64 + lane] = make_float2(A, Bc);
}

// ---- scan fixup: sequential combine of NC chunk summaries per (b, d) ----
__global__ __launch_bounds__(64) void scan_fixup_kernel(
    const float2* __restrict__ chunkAB, float* __restrict__ hinit)
{
    int b = blockIdx.x;
    int d = threadIdx.x;
    const float2* p = chunkAB + (size_t)b * NC * 64 + d;
    float* o = hinit + (size_t)b * NC * 64 + d;

    float h = 0.f;  // h0 = 0
    for (int c0 = 0; c0 < NC; c0 += 8) {
        float2 ab[8];
#pragma unroll
        for (int k = 0; k < 8; ++k) ab[k] = p[(size_t)(c0 + k) * 64];
#pragma unroll
        for (int k = 0; k < 8; ++k) {
            o[(size_t)(c0 + k) * 64] = h;
            h = fmaf(ab[k].x, h, ab[k].y);
        }
    }
}

// ---- scan pass 2: replay chunk from hinit, fused maxabs-normalize ----
__global__ __launch_bounds__(256) void scan_pass2_kernel(
    const float2* __restrict__ zh, const float* __restrict__ hinit,
    float* __restrict__ out, int T)
{
    int lane = threadIdx.x & 63;
    int wid = blockIdx.x * (blockDim.x >> 6) + (threadIdx.x >> 6);  // b*NC + c
    int b = wid / NC, c = wid % NC;
    const float2* p = zh + ((size_t)b * T + (size_t)c * CL) * 64 + lane;
    float* o = out + ((size_t)b * T + (size_t)c * CL) * 64 + lane;

    float h = hinit[(size_t)wid * 64 + lane];
    for (int k0 = 0; k0 < CL; k0 += 8) {
        float2 v[8];
        float hs[8];
#pragma unroll
        for (int k = 0; k < 8; ++k) v[k] = p[(size_t)(k0 + k) * 64];
#pragma unroll
        for (int k = 0; k < 8; ++k) {
            h = fmaf(v[k].x, v[k].y - h, h);   // h += z*(hbar - h)
            hs[k] = h;
        }
#pragma unroll
        for (int k = 0; k < 8; ++k) {
            float m = fabsf(hs[k]);
            m = fmaxf(m, __shfl_xor(m, 32, 64));
            m = fmaxf(m, __shfl_xor(m, 16, 64));
            m = fmaxf(m, __shfl_xor(m, 8, 64));
            m = fmaxf(m, __shfl_xor(m, 4, 64));
            m = fmaxf(m, __shfl_xor(m, 2, 64));
            m = fmaxf(m, __shfl_xor(m, 1, 64));
            o[(size_t)(k0 + k) * 64] = hs[k] / (m + 1e-6f);
        }
    }
}

extern "C" void kernel_launch(void* const* d_in, const int* in_sizes, int n_in,
                              void* d_out, int out_size, void* d_ws, size_t ws_size,
                              hipStream_t stream) {
    const float* x    = (const float*)d_in[0];
    const float* vz0  = (const float*)d_in[1];
    const float* vh0  = (const float*)d_in[2];
    const float* vz1  = (const float*)d_in[3];
    const float* vh1  = (const float*)d_in[4];
    const float* vz2  = (const float*)d_in[5];
    const float* vh2  = (const float*)d_in[6];
    const float* vout = (const float*)d_in[7];

    const int N = in_sizes[0] / 64;   // B*T = 16384
    const int T = NC * CL;            // 2048
    const int B = N / T;              // 8

    char* ws = (char*)d_ws;
    const size_t TAB_ELEMS = (size_t)64 * 15 * 64;   // 61440
    float2* zh      = (float2*)ws;                                  // 8 MB
    float*  cur     = (float*)(ws + 8388608);                       // 4 MB
    float4* tab0    = (float4*)(ws + 12582912);                     // 960 KB
    float4* tab1    = (float4*)(ws + 13565952);                     // 960 KB
    uint2*  tab2    = (uint2*)(ws + 14548992);                      // 480 KB
    unsigned int* tab_out = (unsigned int*)(ws + 15040512);         // 240 KB
    float2* chunkAB = (float2*)(ws + 15286272);                     // 256 KB
    float*  hinit   = (float*)(ws + 15548416);                      // 128 KB

    dim3 pblk(256), pgrd((TAB_ELEMS + 255) / 256);
    prep_dual_kernel<<<pgrd, pblk, 0, stream>>>(vz0, vh0, tab0);
    prep_dual_kernel<<<pgrd, pblk, 0, stream>>>(vz1, vh1, tab1);
    prep_dual_l3_kernel<<<pgrd, pblk, 0, stream>>>(vz2, vh2, tab2);
    prep_out_kernel<<<pgrd, pblk, 0, stream>>>(vout, tab_out);

    dim3 ablk(64 * WPB), agrd((N + WPB - 1) / WPB);
    dim3 sblk(256), sgrd(B * NC / 4);   // 4 waves (chunks) per block

    const float* layer_in = x;
    for (int l = 0; l < 3; ++l) {
        if (l < 2) {
            const float4* tab = (l == 0) ? tab0 : tab1;
            apl_dual_kernel<<<agrd, ablk, 0, stream>>>(layer_in, tab, zh, N);
        } else {
            apl_dual_l3_kernel<<<agrd, ablk, 0, stream>>>(layer_in, tab2, zh, N);
        }
        scan_pass1_kernel<<<sgrd, sblk, 0, stream>>>(zh, chunkAB, T);
        scan_fixup_kernel<<<B, 64, 0, stream>>>(chunkAB, hinit);
        scan_pass2_kernel<<<sgrd, sblk, 0, stream>>>(zh, hinit, cur, T);
        layer_in = cur;
    }
    apl_out_kernel<<<agrd, ablk, 0, stream>>>(cur, tab_out, (float*)d_out, N);
}